// Round 2
// baseline (138.204 us; speedup 1.0000x reference)
//
#include <hip/hip_runtime.h>

// ModelInverse: invert monotone MLP CDF F(x) for 2M targets.
// Strategy: F is sample-independent -> tabulate A(x) on 2^16+1 grid,
// build inverse table G on a uniform z-grid, then per-sample lerp lookup.
//
// ws layout (floats): WE2[4096] | WE1[64] | WE3[64] | T[65537] | G[65537]
//
// R2 changes vs R1:
//  - build_table: 2 waves cooperate per 128 entries (sub-major split of the
//    64-row W2 loop) -> 2 waves/SIMD instead of 1; row address stays
//    wave-uniform so W2 reads remain s_load (scalar pipe) feeding v_fmac.
//  - #pragma unroll 4 on the row loop to batch s_loads ahead of use.
//  - apply: float4-vectorized (4 samples/thread).

#define MONO 1e-3f
#define MLOG2 16
#define MSZ (1 << MLOG2)   // forward table: T[0..MSZ]
#define KSZ MSZ            // inverse table: G[0..KSZ]

#define WS_WE2 0
#define WS_WE1 4096
#define WS_WE3 (4096 + 64)
#define WS_T   (4096 + 128)
#define WS_G   (WS_T + MSZ + 1)

__device__ __forceinline__ float sigmoidf_(float t) {
    return 1.0f / (1.0f + __expf(-t));
}

__global__ __launch_bounds__(256) void exp_weights_kernel(
        const float* __restrict__ pw1,
        const float* __restrict__ pw2,
        const float* __restrict__ pw3,
        float* __restrict__ ws) {
    int i = blockIdx.x * blockDim.x + threadIdx.x;
    if (i < 4096) ws[WS_WE2 + i] = expf(pw2[i]);
    if (i < 64) {
        ws[WS_WE1 + i] = expf(pw1[i]);  // pre_w1 is (64,1) flat
        ws[WS_WE3 + i] = expf(pw3[i]);  // pre_w3 is (1,64) flat
    }
}

// T[j] = sigmoid(w3 . sigmoid(W2 . sigmoid(x*w1+b1) + b2) + b3) + MONO*x
// Block = 256 threads = 128 entries x 2 subs (sub-major: sub = tid>>7 so the
// W2 row index is wave-uniform -> scalar loads). Each sub handles 32 of the
// 64 W2 rows; partials combined through LDS.
__global__ __launch_bounds__(256) void build_table_kernel(
        const float* __restrict__ b1,
        const float* __restrict__ b2,
        const float* __restrict__ b3,
        const float* __restrict__ ws,
        float* __restrict__ T) {
    const float* __restrict__ WE2 = ws + WS_WE2;
    const float* __restrict__ WE1 = ws + WS_WE1;
    const float* __restrict__ WE3 = ws + WS_WE3;

    int tid = threadIdx.x;
    int sub = tid >> 7;        // 0 for waves 0-1, 1 for waves 2-3
    int el  = tid & 127;
    int j = blockIdx.x * 128 + el;

    __shared__ float part[256];

    float x = 0.0f;
    float acc3 = 0.0f;
    if (j <= MSZ) {
        x = (float)j * (1.0f / (float)MSZ);

        float h1[64];
#pragma unroll
        for (int k = 0; k < 64; ++k)
            h1[k] = sigmoidf_(fmaf(x, WE1[k], b1[k]));

        const float* __restrict__ w2base = WE2 + sub * 32 * 64;
        const float* __restrict__ b2base = b2 + sub * 32;
        const float* __restrict__ w3base = WE3 + sub * 32;
#pragma unroll 4
        for (int r = 0; r < 32; ++r) {   // r, sub uniform -> s_load weights
            float acc = b2base[r];
            const float* __restrict__ wrow = w2base + r * 64;
#pragma unroll
            for (int jj = 0; jj < 64; ++jj)
                acc = fmaf(wrow[jj], h1[jj], acc);
            acc3 = fmaf(w3base[r], sigmoidf_(acc), acc3);
        }
    }
    part[tid] = acc3;
    __syncthreads();
    if (tid < 128 && j <= MSZ) {
        float s = part[tid] + part[tid + 128] + b3[0];
        T[j] = sigmoidf_(s) + MONO * x;
    }
}

// G[k] = x such that F(x) = k/KSZ, via binary search in T + in-cell lerp.
__global__ __launch_bounds__(256) void invert_table_kernel(
        const float* __restrict__ T,
        float* __restrict__ G) {
    int k = blockIdx.x * blockDim.x + threadIdx.x;
    if (k > KSZ) return;
    float a0 = T[0];
    float a1 = T[MSZ];
    float zt = fmaf((float)k * (1.0f / (float)KSZ), a1 - a0, a0);

    int lo = 0;
#pragma unroll
    for (int s = MSZ >> 1; s >= 1; s >>= 1) {
        int cand = lo + s;             // cand <= MSZ-1 always
        if (T[cand] <= zt) lo = cand;
    }
    float tl = T[lo];
    float th = T[lo + 1];
    float d = th - tl;
    float t = (d > 1e-30f) ? (zt - tl) / d : 0.5f;
    t = fminf(fmaxf(t, 0.0f), 1.0f);
    G[k] = ((float)lo + t) * (1.0f / (float)MSZ);
}

__device__ __forceinline__ float apply_one(float zv, const float* __restrict__ G) {
    float u = zv * (float)KSZ;
    u = fminf(fmaxf(u, 0.0f), (float)KSZ);
    int k = (int)u;
    if (k > KSZ - 1) k = KSZ - 1;
    float frac = u - (float)k;
    float g0 = G[k];
    float g1 = G[k + 1];
    return fmaf(frac, g1 - g0, g0);
}

__global__ __launch_bounds__(256) void apply_kernel(
        const float* __restrict__ z,
        const float* __restrict__ G,
        float* __restrict__ out, int n) {
    int i = blockIdx.x * blockDim.x + threadIdx.x;
    int base = i * 4;
    if (base + 3 < n) {
        float4 zz = *reinterpret_cast<const float4*>(z + base);
        float4 oo;
        oo.x = apply_one(zz.x, G);
        oo.y = apply_one(zz.y, G);
        oo.z = apply_one(zz.z, G);
        oo.w = apply_one(zz.w, G);
        *reinterpret_cast<float4*>(out + base) = oo;
    } else {
        for (int t = base; t < n; ++t)
            out[t] = apply_one(z[t], G);
    }
}

extern "C" void kernel_launch(void* const* d_in, const int* in_sizes, int n_in,
                              void* d_out, int out_size, void* d_ws, size_t ws_size,
                              hipStream_t stream) {
    const float* z   = (const float*)d_in[0];
    const float* pw1 = (const float*)d_in[1];
    const float* b1  = (const float*)d_in[2];
    const float* pw2 = (const float*)d_in[3];
    const float* b2  = (const float*)d_in[4];
    const float* pw3 = (const float*)d_in[5];
    const float* b3  = (const float*)d_in[6];
    float* out = (float*)d_out;
    float* ws  = (float*)d_ws;
    int n = in_sizes[0];

    exp_weights_kernel<<<16, 256, 0, stream>>>(pw1, pw2, pw3, ws);
    build_table_kernel<<<(MSZ + 1 + 127) / 128, 256, 0, stream>>>(
        b1, b2, b3, ws, ws + WS_T);
    invert_table_kernel<<<(KSZ + 1 + 255) / 256, 256, 0, stream>>>(
        ws + WS_T, ws + WS_G);
    int nv = (n + 3) / 4;
    apply_kernel<<<(nv + 255) / 256, 256, 0, stream>>>(z, ws + WS_G, out, n);
}

// Round 3
// 121.667 us; speedup vs baseline: 1.1359x; 1.1359x over previous
//
#include <hip/hip_runtime.h>

// ModelInverse: invert monotone MLP CDF F(x) for 2M targets.
// Strategy: F is sample-independent -> tabulate A(x) on 2^16+1 grid,
// build inverse table G on a uniform z-grid, then per-sample lerp lookup.
//
// ws layout (floats): WE2[4096] | WE1[64] | WE3[64] | T[65537] | G[65537]
//
// R3 changes vs R2:
//  - build_table: 8 waves per 64 entries (block=512). Row-chunk index sub is
//    forced into an SGPR via __builtin_amdgcn_readfirstlane so W2/W3/b2 reads
//    are provably scalar (s_load on the scalar pipe) -- R2's tid>>7 defeated
//    divergence analysis and fell back to per-lane VMEM (VALUBusy 20%).
//  - 1025 blocks x 8 waves -> ~4-5x occupancy vs R2's grid-limited 2 blk/CU.

#define MONO 1e-3f
#define MLOG2 16
#define MSZ (1 << MLOG2)   // forward table: T[0..MSZ]
#define KSZ MSZ            // inverse table: G[0..KSZ]

#define WS_WE2 0
#define WS_WE1 4096
#define WS_WE3 (4096 + 64)
#define WS_T   (4096 + 128)
#define WS_G   (WS_T + MSZ + 1)

__device__ __forceinline__ float sigmoidf_(float t) {
    return 1.0f / (1.0f + __expf(-t));
}

__global__ __launch_bounds__(256) void exp_weights_kernel(
        const float* __restrict__ pw1,
        const float* __restrict__ pw2,
        const float* __restrict__ pw3,
        float* __restrict__ ws) {
    int i = blockIdx.x * blockDim.x + threadIdx.x;
    if (i < 4096) ws[WS_WE2 + i] = expf(pw2[i]);
    if (i < 64) {
        ws[WS_WE1 + i] = expf(pw1[i]);  // pre_w1 is (64,1) flat
        ws[WS_WE3 + i] = expf(pw3[i]);  // pre_w3 is (1,64) flat
    }
}

// T[j] = sigmoid(w3 . sigmoid(W2 . sigmoid(x*w1+b1) + b2) + b3) + MONO*x
// Block = 512 threads = 8 waves; wave `sub` handles rows [8*sub, 8*sub+8) for
// 64 entries (lane = entry). Partials combined through LDS by wave 0.
__global__ __launch_bounds__(512) void build_table_kernel(
        const float* __restrict__ b1,
        const float* __restrict__ b2,
        const float* __restrict__ b3,
        const float* __restrict__ ws,
        float* __restrict__ T) {
    const float* __restrict__ WE2 = ws + WS_WE2;
    const float* __restrict__ WE1 = ws + WS_WE1;
    const float* __restrict__ WE3 = ws + WS_WE3;

    int tid  = threadIdx.x;
    int lane = tid & 63;
    // Wave-uniform by construction; readfirstlane forces it into an SGPR so
    // all weight addressing below is provably scalar -> s_load.
    int sub = __builtin_amdgcn_readfirstlane(tid >> 6);   // 0..7
    int j = blockIdx.x * 64 + lane;

    __shared__ float part[512];

    float x = 0.0f;
    float acc3 = 0.0f;
    if (j <= MSZ) {
        x = (float)j * (1.0f / (float)MSZ);

        float h1[64];
#pragma unroll
        for (int k = 0; k < 64; ++k)
            h1[k] = sigmoidf_(fmaf(x, WE1[k], b1[k]));

        const float* __restrict__ w2base = WE2 + sub * (8 * 64);
        const float* __restrict__ b2base = b2 + sub * 8;
        const float* __restrict__ w3base = WE3 + sub * 8;
#pragma unroll
        for (int r = 0; r < 8; ++r) {     // r const, sub SGPR -> s_load rows
            float acc = b2base[r];
            const float* __restrict__ wrow = w2base + r * 64;
#pragma unroll
            for (int jj = 0; jj < 64; ++jj)
                acc = fmaf(wrow[jj], h1[jj], acc);
            acc3 = fmaf(w3base[r], sigmoidf_(acc), acc3);
        }
    }
    part[sub * 64 + lane] = acc3;
    __syncthreads();
    if (tid < 64 && j <= MSZ) {
        float s = b3[0];
#pragma unroll
        for (int p = 0; p < 8; ++p)       // stride-64 reads: conflict-free
            s += part[p * 64 + lane];
        T[j] = sigmoidf_(s) + MONO * x;
    }
}

// G[k] = x such that F(x) = k/KSZ, via binary search in T + in-cell lerp.
__global__ __launch_bounds__(256) void invert_table_kernel(
        const float* __restrict__ T,
        float* __restrict__ G) {
    int k = blockIdx.x * blockDim.x + threadIdx.x;
    if (k > KSZ) return;
    float a0 = T[0];
    float a1 = T[MSZ];
    float zt = fmaf((float)k * (1.0f / (float)KSZ), a1 - a0, a0);

    int lo = 0;
#pragma unroll
    for (int s = MSZ >> 1; s >= 1; s >>= 1) {
        int cand = lo + s;             // cand <= MSZ-1 always
        if (T[cand] <= zt) lo = cand;
    }
    float tl = T[lo];
    float th = T[lo + 1];
    float d = th - tl;
    float t = (d > 1e-30f) ? (zt - tl) / d : 0.5f;
    t = fminf(fmaxf(t, 0.0f), 1.0f);
    G[k] = ((float)lo + t) * (1.0f / (float)MSZ);
}

__device__ __forceinline__ float apply_one(float zv, const float* __restrict__ G) {
    float u = zv * (float)KSZ;
    u = fminf(fmaxf(u, 0.0f), (float)KSZ);
    int k = (int)u;
    if (k > KSZ - 1) k = KSZ - 1;
    float frac = u - (float)k;
    float g0 = G[k];
    float g1 = G[k + 1];
    return fmaf(frac, g1 - g0, g0);
}

__global__ __launch_bounds__(256) void apply_kernel(
        const float* __restrict__ z,
        const float* __restrict__ G,
        float* __restrict__ out, int n) {
    int i = blockIdx.x * blockDim.x + threadIdx.x;
    int base = i * 4;
    if (base + 3 < n) {
        float4 zz = *reinterpret_cast<const float4*>(z + base);
        float4 oo;
        oo.x = apply_one(zz.x, G);
        oo.y = apply_one(zz.y, G);
        oo.z = apply_one(zz.z, G);
        oo.w = apply_one(zz.w, G);
        *reinterpret_cast<float4*>(out + base) = oo;
    } else {
        for (int t = base; t < n; ++t)
            out[t] = apply_one(z[t], G);
    }
}

extern "C" void kernel_launch(void* const* d_in, const int* in_sizes, int n_in,
                              void* d_out, int out_size, void* d_ws, size_t ws_size,
                              hipStream_t stream) {
    const float* z   = (const float*)d_in[0];
    const float* pw1 = (const float*)d_in[1];
    const float* b1  = (const float*)d_in[2];
    const float* pw2 = (const float*)d_in[3];
    const float* b2  = (const float*)d_in[4];
    const float* pw3 = (const float*)d_in[5];
    const float* b3  = (const float*)d_in[6];
    float* out = (float*)d_out;
    float* ws  = (float*)d_ws;
    int n = in_sizes[0];

    exp_weights_kernel<<<16, 256, 0, stream>>>(pw1, pw2, pw3, ws);
    build_table_kernel<<<(MSZ + 1 + 63) / 64, 512, 0, stream>>>(
        b1, b2, b3, ws, ws + WS_T);
    invert_table_kernel<<<(KSZ + 1 + 255) / 256, 256, 0, stream>>>(
        ws + WS_T, ws + WS_G);
    int nv = (n + 3) / 4;
    apply_kernel<<<(nv + 255) / 256, 256, 0, stream>>>(z, ws + WS_G, out, n);
}

// Round 4
// 105.560 us; speedup vs baseline: 1.3092x; 1.1526x over previous
//
#include <hip/hip_runtime.h>

// ModelInverse: invert monotone MLP CDF F(x) for 2M targets.
// Strategy: F is sample-independent -> tabulate A(x) on 2^16+1 grid,
// build inverse table G on a uniform z-grid, then per-sample lerp lookup.
//
// ws layout (floats): WE2[4096] | WE1[64] | WE3[64] | T[65537] | G[65537]
//
// R4 changes vs R3 (counters showed VGPR_Count=40 + no scratch traffic ->
// compiler REMATERIALIZED h1 sigmoids per consumer instead of keeping them
// resident; plus each sigmoid paid an IEEE divide chain):
//  - h1 is an ext_vector_type(64) float SSA value (not an alloca) so it
//    cannot be demoted/remat'd; __launch_bounds__(256,4) gives 128 VGPRs.
//  - sigmoid = __expf + v_rcp_f32 (4 instr) instead of exp + IEEE div (~30).
//  - S=4 row-split (block=256: 4 waves x 16 rows) cuts h1 redundancy 2x vs
//    R3's 8-way while keeping 4 blocks/CU occupancy.

#define MONO 1e-3f
#define MLOG2 16
#define MSZ (1 << MLOG2)   // forward table: T[0..MSZ]
#define KSZ MSZ            // inverse table: G[0..KSZ]

#define WS_WE2 0
#define WS_WE1 4096
#define WS_WE3 (4096 + 64)
#define WS_T   (4096 + 128)
#define WS_G   (WS_T + MSZ + 1)

typedef float fvec64 __attribute__((ext_vector_type(64)));

__device__ __forceinline__ float fast_rcp(float x) {
#if __has_builtin(__builtin_amdgcn_rcpf)
    return __builtin_amdgcn_rcpf(x);   // v_rcp_f32, ~1 ulp
#else
    return 1.0f / x;
#endif
}

__device__ __forceinline__ float sigmoidf_(float t) {
    return fast_rcp(1.0f + __expf(-t));   // v_mul+v_exp+v_add+v_rcp
}

__global__ __launch_bounds__(256) void exp_weights_kernel(
        const float* __restrict__ pw1,
        const float* __restrict__ pw2,
        const float* __restrict__ pw3,
        float* __restrict__ ws) {
    int i = blockIdx.x * blockDim.x + threadIdx.x;
    if (i < 4096) ws[WS_WE2 + i] = expf(pw2[i]);
    if (i < 64) {
        ws[WS_WE1 + i] = expf(pw1[i]);  // pre_w1 is (64,1) flat
        ws[WS_WE3 + i] = expf(pw3[i]);  // pre_w3 is (1,64) flat
    }
}

// T[j] = sigmoid(w3 . sigmoid(W2 . sigmoid(x*w1+b1) + b2) + b3) + MONO*x
// Block = 256 threads = 4 waves; wave `sub` handles rows [16*sub, 16*sub+16)
// for 64 entries (lane = entry). Partials combined through LDS.
__global__ __launch_bounds__(256, 4) void build_table_kernel(
        const float* __restrict__ b1,
        const float* __restrict__ b2,
        const float* __restrict__ b3,
        const float* __restrict__ ws,
        float* __restrict__ T) {
    const float* __restrict__ WE2 = ws + WS_WE2;
    const float* __restrict__ WE1 = ws + WS_WE1;
    const float* __restrict__ WE3 = ws + WS_WE3;

    int tid  = threadIdx.x;
    int lane = tid & 63;
    // Wave-uniform; readfirstlane pins it to an SGPR so weight addressing is
    // provably scalar (s_load).
    int sub = __builtin_amdgcn_readfirstlane(tid >> 6);   // 0..3
    int j = blockIdx.x * 64 + lane;
    int jc = j <= MSZ ? j : MSZ;       // clamp; store is guarded below
    float x = (float)jc * (1.0f / (float)MSZ);

    // h1 as an SSA vector value: cannot be demoted to scratch or remat'd.
    fvec64 h1;
#pragma unroll
    for (int k = 0; k < 64; ++k)
        h1[k] = sigmoidf_(fmaf(x, WE1[k], b1[k]));

    const float* __restrict__ w2base = WE2 + sub * (16 * 64);
    const float* __restrict__ b2base = b2 + sub * 16;
    const float* __restrict__ w3base = WE3 + sub * 16;
    float acc3 = 0.0f;
#pragma unroll
    for (int r = 0; r < 16; ++r) {     // r const, sub SGPR -> s_load rows
        float acc = b2base[r];
        const float* __restrict__ wrow = w2base + r * 64;
#pragma unroll
        for (int jj = 0; jj < 64; ++jj)
            acc = fmaf(wrow[jj], h1[jj], acc);
        acc3 = fmaf(w3base[r], sigmoidf_(acc), acc3);
    }

    __shared__ float part[256];
    part[sub * 64 + lane] = acc3;
    __syncthreads();
    if (tid < 64 && j <= MSZ) {
        float s = part[lane] + part[64 + lane] + part[128 + lane]
                + part[192 + lane] + b3[0];
        T[j] = sigmoidf_(s) + MONO * x;
    }
}

// G[k] = x such that F(x) = k/KSZ, via binary search in T + in-cell lerp.
__global__ __launch_bounds__(256) void invert_table_kernel(
        const float* __restrict__ T,
        float* __restrict__ G) {
    int k = blockIdx.x * blockDim.x + threadIdx.x;
    if (k > KSZ) return;
    float a0 = T[0];
    float a1 = T[MSZ];
    float zt = fmaf((float)k * (1.0f / (float)KSZ), a1 - a0, a0);

    int lo = 0;
#pragma unroll
    for (int s = MSZ >> 1; s >= 1; s >>= 1) {
        int cand = lo + s;             // cand <= MSZ-1 always
        if (T[cand] <= zt) lo = cand;
    }
    float tl = T[lo];
    float th = T[lo + 1];
    float d = th - tl;
    float t = (d > 1e-30f) ? (zt - tl) / d : 0.5f;
    t = fminf(fmaxf(t, 0.0f), 1.0f);
    G[k] = ((float)lo + t) * (1.0f / (float)MSZ);
}

__device__ __forceinline__ float apply_one(float zv, const float* __restrict__ G) {
    float u = zv * (float)KSZ;
    u = fminf(fmaxf(u, 0.0f), (float)KSZ);
    int k = (int)u;
    if (k > KSZ - 1) k = KSZ - 1;
    float frac = u - (float)k;
    float g0 = G[k];
    float g1 = G[k + 1];
    return fmaf(frac, g1 - g0, g0);
}

__global__ __launch_bounds__(256) void apply_kernel(
        const float* __restrict__ z,
        const float* __restrict__ G,
        float* __restrict__ out, int n) {
    int i = blockIdx.x * blockDim.x + threadIdx.x;
    int base = i * 4;
    if (base + 3 < n) {
        float4 zz = *reinterpret_cast<const float4*>(z + base);
        float4 oo;
        oo.x = apply_one(zz.x, G);
        oo.y = apply_one(zz.y, G);
        oo.z = apply_one(zz.z, G);
        oo.w = apply_one(zz.w, G);
        *reinterpret_cast<float4*>(out + base) = oo;
    } else {
        for (int t = base; t < n; ++t)
            out[t] = apply_one(z[t], G);
    }
}

extern "C" void kernel_launch(void* const* d_in, const int* in_sizes, int n_in,
                              void* d_out, int out_size, void* d_ws, size_t ws_size,
                              hipStream_t stream) {
    const float* z   = (const float*)d_in[0];
    const float* pw1 = (const float*)d_in[1];
    const float* b1  = (const float*)d_in[2];
    const float* pw2 = (const float*)d_in[3];
    const float* b2  = (const float*)d_in[4];
    const float* pw3 = (const float*)d_in[5];
    const float* b3  = (const float*)d_in[6];
    float* out = (float*)d_out;
    float* ws  = (float*)d_ws;
    int n = in_sizes[0];

    exp_weights_kernel<<<16, 256, 0, stream>>>(pw1, pw2, pw3, ws);
    build_table_kernel<<<(MSZ + 1 + 63) / 64, 256, 0, stream>>>(
        b1, b2, b3, ws, ws + WS_T);
    invert_table_kernel<<<(KSZ + 1 + 255) / 256, 256, 0, stream>>>(
        ws + WS_T, ws + WS_G);
    int nv = (n + 3) / 4;
    apply_kernel<<<(nv + 255) / 256, 256, 0, stream>>>(z, ws + WS_G, out, n);
}